// Round 5
// baseline (380.103 us; speedup 1.0000x reference)
//
#include <hip/hip_runtime.h>
#include <hip/hip_bf16.h>
#include <math.h>

#define BSZ 8
#define DDIM 512
#define NND 2048
#define EE 8
#define LLH 64
#define NEDGE 524288
#define BNN 16384          // BSZ*NND
#define ETOT 540672        // NEDGE + BNN
#define OCC 1536           // 3*EE*LLH
#define DQ 16384           // per-third flat d dimension
#define NCHK 86            // attnS node-chunks (8 nodes = 192 f each, covers n 0..682)

typedef __attribute__((ext_vector_type(8))) short short8;
typedef __attribute__((ext_vector_type(4))) float f32x4;

__device__ inline void atomicMaxF(float* addr, float v) {
    if (v >= 0.f) atomicMax((int*)addr, __float_as_int(v));
    else atomicMin((unsigned int*)addr, (unsigned int)__float_as_int(v));
}

__device__ inline unsigned short f2bf(float x) {
    __hip_bfloat16 h = __float2bfloat16(x);
    return __builtin_bit_cast(unsigned short, h);
}
__device__ inline float bf2f(unsigned short u) {
    return __uint_as_float(((unsigned int)u) << 16);
}

// ---- 1. skeleton = latent @ W_dense + b_dense -> [8, 2048] ----
__global__ __launch_bounds__(256) void k_dense(const float* __restrict__ latent,
                                               const float* __restrict__ Wd,
                                               const float* __restrict__ bd,
                                               float* __restrict__ sk) {
    __shared__ float lat[BSZ * DDIM];
    int tid = threadIdx.x;
    for (int i = tid; i < BSZ * DDIM; i += 256) lat[i] = latent[i];
    __syncthreads();
    int n = blockIdx.x * 32 + (tid & 31);
    int b = tid >> 5;
    float acc = 0.f;
    for (int d = 0; d < DDIM; ++d) acc += lat[b * DDIM + d] * Wd[d * NND + n];
    sk[b * NND + n] = acc + bd[n];
}

// ---- 2. conv1d(K=3, Cin=1, Cout=8, SAME) -> x [16384, 8] ----
__global__ void k_conv1(const float* __restrict__ sk, const float* __restrict__ w1,
                        const float* __restrict__ b1, float* __restrict__ xb) {
    int bn = blockIdx.x * 256 + threadIdx.x;
    if (bn >= BNN) return;
    int n = bn & (NND - 1);
    float sm = (n > 0) ? sk[bn - 1] : 0.f;
    float s0 = sk[bn];
    float sp = (n < NND - 1) ? sk[bn + 1] : 0.f;
    #pragma unroll
    for (int e = 0; e < EE; ++e)
        xb[bn * EE + e] = sm * w1[e] + s0 * w1[EE + e] + sp * w1[2 * EE + e] + b1[e];
}

// ---- 3. GAT Q/K/V projections + init of reduction buffers ----
__global__ void k_gatqkv(const float* __restrict__ xb,
                         const float* __restrict__ Wq, const float* __restrict__ bq,
                         const float* __restrict__ Wk, const float* __restrict__ bk,
                         const float* __restrict__ Wv, const float* __restrict__ gbias,
                         float* __restrict__ Qg, float* __restrict__ Kg,
                         float* __restrict__ Vg, float* __restrict__ hg,
                         float* __restrict__ smax, float* __restrict__ ssum) {
    int i = blockIdx.x * 256 + threadIdx.x;
    if (i >= BNN) return;
    float xr[EE];
    #pragma unroll
    for (int c = 0; c < EE; ++c) xr[c] = xb[i * EE + c];
    #pragma unroll
    for (int j = 0; j < EE; ++j) {
        float q = bq[j], k = bk[j], v = 0.f;
        #pragma unroll
        for (int c = 0; c < EE; ++c) {
            q += xr[c] * Wq[c * EE + j];
            k += xr[c] * Wk[c * EE + j];
            v += xr[c] * Wv[c * EE + j];
        }
        Qg[i * EE + j] = (q >= 0.f) ? q : 0.2f * q;
        Kg[i * EE + j] = (k >= 0.f) ? k : 0.2f * k;
        Vg[i * EE + j] = v;
        hg[i * EE + j] = gbias[j];
    }
    smax[i] = -INFINITY;
    ssum[i] = 0.f;
}

// ---- 4. edge scores + segment max ----
__global__ void k_escore(const int* __restrict__ ei, const float* __restrict__ Qg,
                         const float* __restrict__ Kg, float* __restrict__ sc,
                         float* __restrict__ smax) {
    int e = blockIdx.x * 256 + threadIdx.x;
    if (e >= ETOT) return;
    int r, c;
    if (e < NEDGE) { r = ei[e]; c = ei[NEDGE + e]; } else { r = c = e - NEDGE; }
    const float4* Q4 = (const float4*)(Qg + (size_t)r * EE);
    const float4* K4 = (const float4*)(Kg + (size_t)c * EE);
    float4 qa = Q4[0], qb2 = Q4[1], ka = K4[0], kb2 = K4[1];
    float s = qa.x * ka.x + qa.y * ka.y + qa.z * ka.z + qa.w * ka.w
            + qb2.x * kb2.x + qb2.y * kb2.y + qb2.z * kb2.z + qb2.w * kb2.w;
    sc[e] = s;
    atomicMaxF(smax + r, s);
}

// ---- 5. exp + segment sum ----
__global__ void k_eexp(const int* __restrict__ ei, const float* __restrict__ smax,
                       float* __restrict__ sc, float* __restrict__ ssum) {
    int e = blockIdx.x * 256 + threadIdx.x;
    if (e >= ETOT) return;
    int r = (e < NEDGE) ? ei[e] : e - NEDGE;
    float ex = __expf(sc[e] - smax[r]);
    sc[e] = ex;
    atomicAdd(ssum + r, ex);
}

// ---- 6. alpha * V scatter-aggregate (one thread per edge) ----
__global__ void k_eaggr(const int* __restrict__ ei, const float* __restrict__ sc,
                        const float* __restrict__ ssum, const float* __restrict__ Vg,
                        float* __restrict__ hg) {
    int e = blockIdx.x * 256 + threadIdx.x;
    if (e >= ETOT) return;
    int r, c;
    if (e < NEDGE) { r = ei[e]; c = ei[NEDGE + e]; } else { r = c = e - NEDGE; }
    float alpha = sc[e] / ssum[r];
    const float4* V4 = (const float4*)(Vg + (size_t)c * EE);
    float4 v0 = V4[0], v1 = V4[1];
    float* h = hg + (size_t)r * EE;
    atomicAdd(h + 0, alpha * v0.x);
    atomicAdd(h + 1, alpha * v0.y);
    atomicAdd(h + 2, alpha * v0.z);
    atomicAdd(h + 3, alpha * v0.w);
    atomicAdd(h + 4, alpha * v1.x);
    atomicAdd(h + 5, alpha * v1.y);
    atomicAdd(h + 6, alpha * v1.z);
    atomicAdd(h + 7, alpha * v1.w);
}

// ---- 7. qkv conv -> Fnat bf16 [b][n][o], o = l*24+c ----
// grid (64 n-chunks of 32, 8 b), block 256; weights in registers, h window in LDS.
__global__ __launch_bounds__(256) void k_qkvF(const float* __restrict__ hg,
                                              const float* __restrict__ qw,
                                              const float* __restrict__ qb,
                                              unsigned short* __restrict__ Fq) {
    int n0 = blockIdx.x * 32;
    int b = blockIdx.y;
    __shared__ float hs[34 * EE];        // rows n0-1 .. n0+32
    int tid = threadIdx.x;
    for (int i = tid; i < 34 * EE; i += 256) {
        int nn = n0 - 1 + (i >> 3);
        hs[i] = (nn >= 0 && nn < NND) ? hg[((size_t)b * NND + nn) * EE + (i & 7)] : 0.f;
    }
    __syncthreads();
    #pragma unroll
    for (int pass = 0; pass < 2; ++pass) {
        float w[3][24], bias[3];
        #pragma unroll
        for (int rr = 0; rr < 3; ++rr) {
            int o = tid + (pass * 3 + rr) * 256;
            bias[rr] = qb[o];
            #pragma unroll
            for (int kk = 0; kk < 24; ++kk) w[rr][kk] = qw[kk * OCC + o];
        }
        for (int nn = 0; nn < 32; ++nn) {
            const float* hv = &hs[nn * EE];   // 24 contiguous = window of node n0+nn
            float a0 = bias[0], a1 = bias[1], a2 = bias[2];
            #pragma unroll
            for (int kk = 0; kk < 24; ++kk) {
                float h = hv[kk];
                a0 += h * w[0][kk]; a1 += h * w[1][kk]; a2 += h * w[2][kk];
            }
            unsigned short* dst = Fq + ((size_t)b * NND + n0 + nn) * OCC + tid + pass * 768;
            dst[0]   = f2bf(a0);
            dst[256] = f2bf(a1);
            dst[512] = f2bf(a2);
        }
    }
}

// ---- 8. S partials via MFMA: Spart[ch][b][t][s] over 8-node f-chunks ----
// q[t][f=n*24+c] = Fnat[n][t*24+c]; k[s][f] = Fnat[n+1365][s*24+c+8] (c<16)
//                                           / Fnat[n+1366][s*24+c-16] (c>=16)
__global__ __launch_bounds__(256) void k_attnS(const unsigned short* __restrict__ Fq,
                                               float* __restrict__ Spart) {
    int ch = blockIdx.x, b = blockIdx.y;
    int n0 = ch * 8;
    __shared__ unsigned short qt[64 * 200];   // row stride 200 bf16 (2-way banks)
    __shared__ unsigned short kt[64 * 200];
    int tid = threadIdx.x;
    int t = tid & 63, nl0 = tid >> 6;
    const unsigned short* Fb = Fq + (size_t)b * NND * OCC;
    short8 z = {0,0,0,0,0,0,0,0};
    #pragma unroll
    for (int h = 0; h < 2; ++h) {
        int nl = nl0 + h * 4;
        int n = n0 + nl;
        short8 q0 = z, q1 = z, q2 = z;
        if (n <= 682) {
            const short8* p = (const short8*)(Fb + (size_t)n * OCC + t * 24);
            q0 = p[0]; q1 = p[1];
            if (n < 682) q2 = p[2];           // n==682: c>=16 is f>=16384 -> zero
        }
        *(short8*)(&qt[t * 200 + nl * 24 + 0])  = q0;
        *(short8*)(&qt[t * 200 + nl * 24 + 8])  = q1;
        *(short8*)(&qt[t * 200 + nl * 24 + 16]) = q2;
        short8 k0 = z, k1 = z, k2 = z;
        if (n <= 682) {
            const short8* p = (const short8*)(Fb + (size_t)(n + 1365) * OCC + t * 24 + 8);
            k0 = p[0]; k1 = p[1];
        }
        if (n <= 681) {
            const short8* p2 = (const short8*)(Fb + (size_t)(n + 1366) * OCC + t * 24);
            k2 = p2[0];
        }
        *(short8*)(&kt[t * 200 + nl * 24 + 0])  = k0;
        *(short8*)(&kt[t * 200 + nl * 24 + 8])  = k1;
        *(short8*)(&kt[t * 200 + nl * 24 + 16]) = k2;
    }
    __syncthreads();
    int lane = tid & 63, wv = tid >> 6;
    int fr = lane & 15, fk = (lane >> 4) * 8;
    short8 afr[6];
    #pragma unroll
    for (int ks = 0; ks < 6; ++ks)
        afr[ks] = *(const short8*)(&qt[(wv * 16 + fr) * 200 + ks * 32 + fk]);
    #pragma unroll
    for (int srow = 0; srow < 4; ++srow) {
        f32x4 acc = {0.f, 0.f, 0.f, 0.f};
        #pragma unroll
        for (int ks = 0; ks < 6; ++ks) {
            short8 bfr = *(const short8*)(&kt[(srow * 16 + fr) * 200 + ks * 32 + fk]);
            acc = __builtin_amdgcn_mfma_f32_16x16x32_bf16(afr[ks], bfr, acc, 0, 0, 0);
        }
        float* dst = Spart + (((size_t)ch * BSZ + b) * LLH + wv * 16 + (lane >> 4) * 4) * LLH
                   + srow * 16 + fr;
        #pragma unroll
        for (int r = 0; r < 4; ++r) dst[r * LLH] = acc[r];
    }
}

// ---- 9. reduce partials + row softmax -> atT[b][s][t] ----
__global__ void k_softmax(const float* __restrict__ Spart, float* __restrict__ atT) {
    int b = blockIdx.x >> 6, t = blockIdx.x & 63;
    int s = threadIdx.x;
    float v = 0.f;
    for (int ch = 0; ch < NCHK; ++ch)
        v += Spart[(((size_t)ch * BSZ + b) * LLH + t) * LLH + s];
    float m = v;
    #pragma unroll
    for (int off = 32; off > 0; off >>= 1) m = fmaxf(m, __shfl_xor(m, off));
    float e = __expf(v - m);
    float sum = e;
    #pragma unroll
    for (int off = 32; off > 0; off >>= 1) sum += __shfl_xor(sum, off);
    atT[((size_t)b * LLH + s) * LLH + t] = e / sum;
}

// ---- 10. out[b][t][d] = sum_s atT[b][s][t] * v[s][d];  v from Fnat bf16 ----
// grid (256, 8), block 256 = 4 waves(16 t) x 64 lanes(d); atT via uniform s_loads
__global__ __launch_bounds__(256) void k_attnV(const unsigned short* __restrict__ Fq,
                                               const float* __restrict__ atT,
                                               float* __restrict__ out) {
    int b = blockIdx.y;
    int d = blockIdx.x * 64 + (threadIdx.x & 63);
    int t0 = __builtin_amdgcn_readfirstlane((threadIdx.x >> 6) * 16);
    int f = d + DQ;
    int n = f / 24, c = f - n * 24;
    const unsigned short* vcol = Fq + ((size_t)b * NND + n) * OCC + c;
    const float* arow = atT + (size_t)b * LLH * LLH + t0;
    float acc[16];
    #pragma unroll
    for (int tt = 0; tt < 16; ++tt) acc[tt] = 0.f;
    #pragma unroll 4
    for (int s = 0; s < LLH; ++s) {
        float vv = bf2f(vcol[s * 24]);
        #pragma unroll
        for (int tt = 0; tt < 16; ++tt)
            acc[tt] += arow[s * LLH + tt] * vv;   // wave-uniform -> scalar loads
    }
    float* ob = out + ((size_t)b * LLH + t0) * DQ + d;
    #pragma unroll
    for (int tt = 0; tt < 16; ++tt) ob[(size_t)tt * DQ] = acc[tt];
}

extern "C" void kernel_launch(void* const* d_in, const int* in_sizes, int n_in,
                              void* d_out, int out_size, void* d_ws, size_t ws_size,
                              hipStream_t stream) {
    (void)in_sizes; (void)n_in; (void)out_size; (void)ws_size;
    const float* latent = (const float*)d_in[0];
    const int*   ei     = (const int*)d_in[1];
    const float* Wd     = (const float*)d_in[2];
    const float* bd     = (const float*)d_in[3];
    const float* w1     = (const float*)d_in[4];
    const float* b1     = (const float*)d_in[5];
    const float* Wq     = (const float*)d_in[6];
    const float* bq     = (const float*)d_in[7];
    const float* Wk     = (const float*)d_in[8];
    const float* bk     = (const float*)d_in[9];
    const float* Wv     = (const float*)d_in[10];
    const float* gbias  = (const float*)d_in[11];
    const float* qw     = (const float*)d_in[12];
    const float* qb     = (const float*)d_in[13];
    float* out = (float*)d_out;

    float* ws    = (float*)d_ws;
    float* sk    = ws;                         // 16384
    float* xb    = sk + BNN;                   // 131072
    float* Qg    = xb + BNN * EE;              // 131072
    float* Kg    = Qg + BNN * EE;              // 131072
    float* Vg    = Kg + BNN * EE;              // 131072
    float* hg    = Vg + BNN * EE;              // 131072
    float* smax  = hg + BNN * EE;              // 16384
    float* ssum  = smax + BNN;                 // 16384
    float* sc    = ssum + BNN;                 // 540672
    float* Spart = sc + ETOT;                  // 86*8*64*64 = 2818048
    float* atT   = Spart + (size_t)NCHK * BSZ * LLH * LLH;   // 32768
    unsigned short* Fq = (unsigned short*)(atT + BSZ * LLH * LLH);  // 25165824 bf16 (~50 MB)

    k_dense<<<dim3(64), dim3(256), 0, stream>>>(latent, Wd, bd, sk);
    k_conv1<<<dim3(64), dim3(256), 0, stream>>>(sk, w1, b1, xb);
    k_gatqkv<<<dim3(64), dim3(256), 0, stream>>>(xb, Wq, bq, Wk, bk, Wv, gbias,
                                                 Qg, Kg, Vg, hg, smax, ssum);
    k_escore<<<dim3(ETOT / 256), dim3(256), 0, stream>>>(ei, Qg, Kg, sc, smax);
    k_eexp<<<dim3(ETOT / 256), dim3(256), 0, stream>>>(ei, smax, sc, ssum);
    k_eaggr<<<dim3(ETOT / 256), dim3(256), 0, stream>>>(ei, sc, ssum, Vg, hg);
    k_qkvF<<<dim3(64, 8), dim3(256), 0, stream>>>(hg, qw, qb, Fq);
    k_attnS<<<dim3(NCHK, 8), dim3(256), 0, stream>>>(Fq, Spart);
    k_softmax<<<dim3(512), dim3(64), 0, stream>>>(Spart, atT);
    k_attnV<<<dim3(256, 8), dim3(256), 0, stream>>>(Fq, atT, out);
}

// Round 6
// 176.713 us; speedup vs baseline: 2.1510x; 2.1510x over previous
//
#include <hip/hip_runtime.h>
#include <hip/hip_bf16.h>
#include <math.h>

#define BSZ 8
#define DDIM 512
#define NND 2048
#define EE 8
#define LLH 64
#define NEDGE 524288
#define BNN 16384          // BSZ*NND
#define OCC 1536           // 3*EE*LLH
#define DQ 16384           // per-third flat d dimension
#define NCHK 86            // attnS node-chunks (8 nodes = 192 f each, covers n 0..682)

typedef __attribute__((ext_vector_type(8))) short short8;
typedef __attribute__((ext_vector_type(4))) float f32x4;

__device__ inline unsigned short f2bf(float x) {
    __hip_bfloat16 h = __float2bfloat16(x);
    return __builtin_bit_cast(unsigned short, h);
}
__device__ inline float bf2f(unsigned short u) {
    return __uint_as_float(((unsigned int)u) << 16);
}

// ---- 1. skeleton = latent @ W_dense + b_dense -> [8, 2048] ----
__global__ __launch_bounds__(256) void k_dense(const float* __restrict__ latent,
                                               const float* __restrict__ Wd,
                                               const float* __restrict__ bd,
                                               float* __restrict__ sk) {
    __shared__ float lat[BSZ * DDIM];
    int tid = threadIdx.x;
    for (int i = tid; i < BSZ * DDIM; i += 256) lat[i] = latent[i];
    __syncthreads();
    int n = blockIdx.x * 32 + (tid & 31);
    int b = tid >> 5;
    float acc = 0.f;
    for (int d = 0; d < DDIM; ++d) acc += lat[b * DDIM + d] * Wd[d * NND + n];
    sk[b * NND + n] = acc + bd[n];
}

// ---- 2. conv1d(K=3, Cin=1, Cout=8, SAME) -> x [16384, 8] ----
__global__ void k_conv1(const float* __restrict__ sk, const float* __restrict__ w1,
                        const float* __restrict__ b1, float* __restrict__ xb) {
    int bn = blockIdx.x * 256 + threadIdx.x;
    if (bn >= BNN) return;
    int n = bn & (NND - 1);
    float sm = (n > 0) ? sk[bn - 1] : 0.f;
    float s0 = sk[bn];
    float sp = (n < NND - 1) ? sk[bn + 1] : 0.f;
    #pragma unroll
    for (int e = 0; e < EE; ++e)
        xb[bn * EE + e] = sm * w1[e] + s0 * w1[EE + e] + sp * w1[2 * EE + e] + b1[e];
}

// ---- 3. GAT Q/K/V projections + zero the edge histogram ----
__global__ void k_gatqkv(const float* __restrict__ xb,
                         const float* __restrict__ Wq, const float* __restrict__ bq,
                         const float* __restrict__ Wk, const float* __restrict__ bk,
                         const float* __restrict__ Wv,
                         float* __restrict__ Qg, float* __restrict__ Kg,
                         float* __restrict__ Vg, int* __restrict__ hist) {
    int i = blockIdx.x * 256 + threadIdx.x;
    if (i >= BNN) return;
    float xr[EE];
    #pragma unroll
    for (int c = 0; c < EE; ++c) xr[c] = xb[i * EE + c];
    #pragma unroll
    for (int j = 0; j < EE; ++j) {
        float q = bq[j], k = bk[j], v = 0.f;
        #pragma unroll
        for (int c = 0; c < EE; ++c) {
            q += xr[c] * Wq[c * EE + j];
            k += xr[c] * Wk[c * EE + j];
            v += xr[c] * Wv[c * EE + j];
        }
        Qg[i * EE + j] = (q >= 0.f) ? q : 0.2f * q;
        Kg[i * EE + j] = (k >= 0.f) ? k : 0.2f * k;
        Vg[i * EE + j] = v;
    }
    hist[i] = 0;
}

// ---- 4. edge histogram by destination row ----
__global__ void k_hist(const int* __restrict__ ei, int* __restrict__ hist) {
    int e = blockIdx.x * 256 + threadIdx.x;
    if (e >= NEDGE) return;
    atomicAdd(hist + ei[e], 1);
}

// ---- 5. exclusive prefix sum over 16384 counts (single block) ----
__global__ __launch_bounds__(256) void k_scan(const int* __restrict__ hist,
                                              int* __restrict__ offs,
                                              int* __restrict__ cnt) {
    __shared__ int part[256];
    int tid = threadIdx.x;
    int base = tid * 64;
    int sum = 0;
    for (int i = 0; i < 64; ++i) sum += hist[base + i];
    part[tid] = sum;
    __syncthreads();
    for (int off = 1; off < 256; off <<= 1) {
        int v = (tid >= off) ? part[tid - off] : 0;
        __syncthreads();
        part[tid] += v;
        __syncthreads();
    }
    int run = (tid > 0) ? part[tid - 1] : 0;
    for (int i = 0; i < 64; ++i) {
        offs[base + i] = run;
        cnt[base + i] = run;
        run += hist[base + i];
    }
}

// ---- 6. scatter edge columns into destination buckets ----
__global__ void k_scatter(const int* __restrict__ ei, int* __restrict__ cnt,
                          int* __restrict__ ecol) {
    int e = blockIdx.x * 256 + threadIdx.x;
    if (e >= NEDGE) return;
    int r = ei[e], c = ei[NEDGE + e];
    int pos = atomicAdd(cnt + r, 1);
    ecol[pos] = c;
}

// ---- 7. per-row gather + online softmax + aggregate: h[r] = GAT(r) ----
// one 64-lane wave per destination row; lane-per-edge
__global__ __launch_bounds__(256) void k_gatagg(const int* __restrict__ ecol,
                                                const int* __restrict__ offs,
                                                const int* __restrict__ hist,
                                                const float* __restrict__ Qg,
                                                const float* __restrict__ Kg,
                                                const float* __restrict__ Vg,
                                                const float* __restrict__ gbias,
                                                float* __restrict__ hg) {
    int row = __builtin_amdgcn_readfirstlane(blockIdx.x * 4 + (threadIdx.x >> 6));
    int lane = threadIdx.x & 63;
    const float* Qr = Qg + (size_t)row * EE;     // wave-uniform -> scalar loads
    float q0 = Qr[0], q1 = Qr[1], q2 = Qr[2], q3 = Qr[3];
    float q4 = Qr[4], q5 = Qr[5], q6 = Qr[6], q7 = Qr[7];
    int beg = offs[row], deg = hist[row];
    int total = deg + 1;                         // + self-loop
    float m = -INFINITY, l = 0.f;
    float acc[EE];
    #pragma unroll
    for (int j = 0; j < EE; ++j) acc[j] = 0.f;
    for (int base = 0; base < total; base += 64) {
        int idx = base + lane;
        int c = row;                             // self-loop / inactive default (safe addr)
        if (idx < deg) c = ecol[beg + idx];
        const float4* K4 = (const float4*)(Kg + (size_t)c * EE);
        float4 ka = K4[0], kb = K4[1];
        float s = q0*ka.x + q1*ka.y + q2*ka.z + q3*ka.w
                + q4*kb.x + q5*kb.y + q6*kb.z + q7*kb.w;
        if (idx >= total) s = -INFINITY;
        float pm = s;
        #pragma unroll
        for (int off = 32; off > 0; off >>= 1) pm = fmaxf(pm, __shfl_xor(pm, off));
        float nm = fmaxf(m, pm);
        float scale = __expf(m - nm);            // m=-inf -> 0
        float p = (idx < total) ? __expf(s - nm) : 0.f;
        float ps = p;
        #pragma unroll
        for (int off = 32; off > 0; off >>= 1) ps += __shfl_xor(ps, off);
        l = l * scale + ps;
        const float4* V4 = (const float4*)(Vg + (size_t)c * EE);
        float4 va = V4[0], vb = V4[1];
        float pv[EE] = {p*va.x, p*va.y, p*va.z, p*va.w, p*vb.x, p*vb.y, p*vb.z, p*vb.w};
        #pragma unroll
        for (int j = 0; j < EE; ++j) {
            float t = pv[j];
            #pragma unroll
            for (int off = 32; off > 0; off >>= 1) t += __shfl_xor(t, off);
            acc[j] = acc[j] * scale + t;
        }
        m = nm;
    }
    if (lane < EE)
        hg[(size_t)row * EE + lane] = acc[lane] / l + gbias[lane];
}

// ---- 8. qkv conv -> Fnat bf16 [b][n][o], o = l*24+c ----
__global__ __launch_bounds__(256) void k_qkvF(const float* __restrict__ hg,
                                              const float* __restrict__ qw,
                                              const float* __restrict__ qb,
                                              unsigned short* __restrict__ Fq) {
    int n0 = blockIdx.x * 32;
    int b = blockIdx.y;
    __shared__ float hs[34 * EE];        // rows n0-1 .. n0+32
    int tid = threadIdx.x;
    for (int i = tid; i < 34 * EE; i += 256) {
        int nn = n0 - 1 + (i >> 3);
        hs[i] = (nn >= 0 && nn < NND) ? hg[((size_t)b * NND + nn) * EE + (i & 7)] : 0.f;
    }
    __syncthreads();
    #pragma unroll
    for (int pass = 0; pass < 2; ++pass) {
        float w[3][24], bias[3];
        #pragma unroll
        for (int rr = 0; rr < 3; ++rr) {
            int o = tid + (pass * 3 + rr) * 256;
            bias[rr] = qb[o];
            #pragma unroll
            for (int kk = 0; kk < 24; ++kk) w[rr][kk] = qw[kk * OCC + o];
        }
        for (int nn = 0; nn < 32; ++nn) {
            const float* hv = &hs[nn * EE];
            float a0 = bias[0], a1 = bias[1], a2 = bias[2];
            #pragma unroll
            for (int kk = 0; kk < 24; ++kk) {
                float h = hv[kk];
                a0 += h * w[0][kk]; a1 += h * w[1][kk]; a2 += h * w[2][kk];
            }
            unsigned short* dst = Fq + ((size_t)b * NND + n0 + nn) * OCC + tid + pass * 768;
            dst[0]   = f2bf(a0);
            dst[256] = f2bf(a1);
            dst[512] = f2bf(a2);
        }
    }
}

// ---- 9. S partials via MFMA over 8-node f-chunks ----
__global__ __launch_bounds__(256) void k_attnS(const unsigned short* __restrict__ Fq,
                                               float* __restrict__ Spart) {
    int ch = blockIdx.x, b = blockIdx.y;
    int n0 = ch * 8;
    __shared__ unsigned short qt[64 * 200];
    __shared__ unsigned short kt[64 * 200];
    int tid = threadIdx.x;
    int t = tid & 63, nl0 = tid >> 6;
    const unsigned short* Fb = Fq + (size_t)b * NND * OCC;
    short8 z = {0,0,0,0,0,0,0,0};
    #pragma unroll
    for (int h = 0; h < 2; ++h) {
        int nl = nl0 + h * 4;
        int n = n0 + nl;
        short8 q0 = z, q1 = z, q2 = z;
        if (n <= 682) {
            const short8* p = (const short8*)(Fb + (size_t)n * OCC + t * 24);
            q0 = p[0]; q1 = p[1];
            if (n < 682) q2 = p[2];
        }
        *(short8*)(&qt[t * 200 + nl * 24 + 0])  = q0;
        *(short8*)(&qt[t * 200 + nl * 24 + 8])  = q1;
        *(short8*)(&qt[t * 200 + nl * 24 + 16]) = q2;
        short8 k0 = z, k1 = z, k2 = z;
        if (n <= 682) {
            const short8* p = (const short8*)(Fb + (size_t)(n + 1365) * OCC + t * 24 + 8);
            k0 = p[0]; k1 = p[1];
        }
        if (n <= 681) {
            const short8* p2 = (const short8*)(Fb + (size_t)(n + 1366) * OCC + t * 24);
            k2 = p2[0];
        }
        *(short8*)(&kt[t * 200 + nl * 24 + 0])  = k0;
        *(short8*)(&kt[t * 200 + nl * 24 + 8])  = k1;
        *(short8*)(&kt[t * 200 + nl * 24 + 16]) = k2;
    }
    __syncthreads();
    int lane = tid & 63, wv = tid >> 6;
    int fr = lane & 15, fk = (lane >> 4) * 8;
    short8 afr[6];
    #pragma unroll
    for (int ks = 0; ks < 6; ++ks)
        afr[ks] = *(const short8*)(&qt[(wv * 16 + fr) * 200 + ks * 32 + fk]);
    #pragma unroll
    for (int srow = 0; srow < 4; ++srow) {
        f32x4 acc = {0.f, 0.f, 0.f, 0.f};
        #pragma unroll
        for (int ks = 0; ks < 6; ++ks) {
            short8 bfr = *(const short8*)(&kt[(srow * 16 + fr) * 200 + ks * 32 + fk]);
            acc = __builtin_amdgcn_mfma_f32_16x16x32_bf16(afr[ks], bfr, acc, 0, 0, 0);
        }
        float* dst = Spart + (((size_t)ch * BSZ + b) * LLH + wv * 16 + (lane >> 4) * 4) * LLH
                   + srow * 16 + fr;
        #pragma unroll
        for (int r = 0; r < 4; ++r) dst[r * LLH] = acc[r];
    }
}

// ---- 10. reduce partials + row softmax -> atT[b][s][t] ----
__global__ void k_softmax(const float* __restrict__ Spart, float* __restrict__ atT) {
    int b = blockIdx.x >> 6, t = blockIdx.x & 63;
    int s = threadIdx.x;
    float v = 0.f;
    for (int ch = 0; ch < NCHK; ++ch)
        v += Spart[(((size_t)ch * BSZ + b) * LLH + t) * LLH + s];
    float m = v;
    #pragma unroll
    for (int off = 32; off > 0; off >>= 1) m = fmaxf(m, __shfl_xor(m, off));
    float e = __expf(v - m);
    float sum = e;
    #pragma unroll
    for (int off = 32; off > 0; off >>= 1) sum += __shfl_xor(sum, off);
    atT[((size_t)b * LLH + s) * LLH + t] = e / sum;
}

// ---- 11. out[b][t][d] = sum_s atT[b][s][t] * v[s][d] ----
__global__ __launch_bounds__(256) void k_attnV(const unsigned short* __restrict__ Fq,
                                               const float* __restrict__ atT,
                                               float* __restrict__ out) {
    int b = blockIdx.y;
    int d = blockIdx.x * 64 + (threadIdx.x & 63);
    int t0 = __builtin_amdgcn_readfirstlane((threadIdx.x >> 6) * 16);
    int f = d + DQ;
    int n = f / 24, c = f - n * 24;
    const unsigned short* vcol = Fq + ((size_t)b * NND + n) * OCC + c;
    const float* arow = atT + (size_t)b * LLH * LLH + t0;
    float acc[16];
    #pragma unroll
    for (int tt = 0; tt < 16; ++tt) acc[tt] = 0.f;
    #pragma unroll 4
    for (int s = 0; s < LLH; ++s) {
        float vv = bf2f(vcol[s * 24]);
        #pragma unroll
        for (int tt = 0; tt < 16; ++tt)
            acc[tt] += arow[s * LLH + tt] * vv;
    }
    float* ob = out + ((size_t)b * LLH + t0) * DQ + d;
    #pragma unroll
    for (int tt = 0; tt < 16; ++tt) ob[(size_t)tt * DQ] = acc[tt];
}

extern "C" void kernel_launch(void* const* d_in, const int* in_sizes, int n_in,
                              void* d_out, int out_size, void* d_ws, size_t ws_size,
                              hipStream_t stream) {
    (void)in_sizes; (void)n_in; (void)out_size; (void)ws_size;
    const float* latent = (const float*)d_in[0];
    const int*   ei     = (const int*)d_in[1];
    const float* Wd     = (const float*)d_in[2];
    const float* bd     = (const float*)d_in[3];
    const float* w1     = (const float*)d_in[4];
    const float* b1     = (const float*)d_in[5];
    const float* Wq     = (const float*)d_in[6];
    const float* bq     = (const float*)d_in[7];
    const float* Wk     = (const float*)d_in[8];
    const float* bk     = (const float*)d_in[9];
    const float* Wv     = (const float*)d_in[10];
    const float* gbias  = (const float*)d_in[11];
    const float* qw     = (const float*)d_in[12];
    const float* qb     = (const float*)d_in[13];
    float* out = (float*)d_out;

    float* ws    = (float*)d_ws;
    float* sk    = ws;                         // 16384
    float* xb    = sk + BNN;                   // 131072
    float* Qg    = xb + BNN * EE;              // 131072
    float* Kg    = Qg + BNN * EE;              // 131072
    float* Vg    = Kg + BNN * EE;              // 131072
    float* hg    = Vg + BNN * EE;              // 131072
    int*   hist  = (int*)(hg + BNN * EE);      // 16384
    int*   offs  = hist + BNN;                 // 16384
    int*   cnt   = offs + BNN;                 // 16384
    int*   ecol  = cnt + BNN;                  // 524288
    float* Spart = (float*)(ecol + NEDGE);     // 2818048
    float* atT   = Spart + (size_t)NCHK * BSZ * LLH * LLH;   // 32768
    unsigned short* Fq = (unsigned short*)(atT + BSZ * LLH * LLH);  // 25165824 bf16

    k_dense<<<dim3(64), dim3(256), 0, stream>>>(latent, Wd, bd, sk);
    k_conv1<<<dim3(64), dim3(256), 0, stream>>>(sk, w1, b1, xb);
    k_gatqkv<<<dim3(64), dim3(256), 0, stream>>>(xb, Wq, bq, Wk, bk, Wv,
                                                 Qg, Kg, Vg, hist);
    k_hist<<<dim3(NEDGE / 256), dim3(256), 0, stream>>>(ei, hist);
    k_scan<<<dim3(1), dim3(256), 0, stream>>>(hist, offs, cnt);
    k_scatter<<<dim3(NEDGE / 256), dim3(256), 0, stream>>>(ei, cnt, ecol);
    k_gatagg<<<dim3(BNN / 4), dim3(256), 0, stream>>>(ecol, offs, hist,
                                                      Qg, Kg, Vg, gbias, hg);
    k_qkvF<<<dim3(64, 8), dim3(256), 0, stream>>>(hg, qw, qb, Fq);
    k_attnS<<<dim3(NCHK, 8), dim3(256), 0, stream>>>(Fq, Spart);
    k_softmax<<<dim3(512), dim3(64), 0, stream>>>(Spart, atT);
    k_attnV<<<dim3(256, 8), dim3(256), 0, stream>>>(Fq, atT, out);
}

// Round 7
// 146.627 us; speedup vs baseline: 2.5923x; 1.2052x over previous
//
#include <hip/hip_runtime.h>
#include <hip/hip_bf16.h>
#include <math.h>

#define BSZ 8
#define DDIM 512
#define NND 2048
#define EE 8
#define LLH 64
#define NEDGE 524288
#define BNN 16384          // BSZ*NND
#define OCC 1536           // 3*EE*LLH
#define DQ 16384           // per-third flat d dimension
#define NCHK 22            // attnS node-chunks (32 nodes = 768 f each, covers n 0..703)

typedef __attribute__((ext_vector_type(8))) short short8;
typedef __attribute__((ext_vector_type(4))) float f32x4;

__device__ inline unsigned short f2bf(float x) {
    __hip_bfloat16 h = __float2bfloat16(x);
    return __builtin_bit_cast(unsigned short, h);
}
__device__ inline float bf2f(unsigned short u) {
    return __uint_as_float(((unsigned int)u) << 16);
}

// ---- 1. dense partials: pdense[ds][b][n] = sum_{d in 64-chunk} latent[b][d] W[d][n] ----
// grid (64 n-blocks, 8 d-splits), block 256 = 32 n x 8 b
__global__ __launch_bounds__(256) void k_densep(const float* __restrict__ latent,
                                                const float* __restrict__ Wd,
                                                float* __restrict__ pdense) {
    int n0 = blockIdx.x * 32, d0 = blockIdx.y * 64;
    __shared__ float lat[8][64];
    int tid = threadIdx.x;
    #pragma unroll
    for (int r = 0; r < 2; ++r) {
        int i = r * 256 + tid;
        lat[i >> 6][i & 63] = latent[(i >> 6) * DDIM + d0 + (i & 63)];
    }
    __syncthreads();
    int nl = tid & 31, b = tid >> 5;
    const float* wp = Wd + (size_t)d0 * NND + n0 + nl;
    float acc = 0.f;
    #pragma unroll 8
    for (int d = 0; d < 64; ++d) acc += lat[b][d] * wp[(size_t)d * NND];
    pdense[((size_t)blockIdx.y * BSZ + b) * NND + n0 + nl] = acc;
}

// ---- 2. fused: reduce dense partials + bias -> conv1d(K=3,Cin=1,Cout=8)
//          -> GAT Q/K/V projections + hist zero ----
__global__ __launch_bounds__(64) void k_gat(const float* __restrict__ pdense,
                                            const float* __restrict__ bd,
                                            const float* __restrict__ w1,
                                            const float* __restrict__ b1,
                                            const float* __restrict__ Wq, const float* __restrict__ bq,
                                            const float* __restrict__ Wk, const float* __restrict__ bk,
                                            const float* __restrict__ Wv,
                                            float* __restrict__ Qg, float* __restrict__ Kg,
                                            float* __restrict__ Vg, int* __restrict__ hist) {
    int i = blockIdx.x * 64 + threadIdx.x;
    int b = i >> 11, n = i & (NND - 1);
    float sm = 0.f, s0 = 0.f, sp = 0.f;
    #pragma unroll
    for (int ds = 0; ds < 8; ++ds) {
        const float* p = pdense + ((size_t)ds * BSZ + b) * NND + n;
        if (n > 0) sm += p[-1];
        s0 += p[0];
        if (n < NND - 1) sp += p[1];
    }
    if (n > 0) sm += bd[n - 1];
    s0 += bd[n];
    if (n < NND - 1) sp += bd[n + 1];
    float xr[EE];
    #pragma unroll
    for (int e = 0; e < EE; ++e)
        xr[e] = sm * w1[e] + s0 * w1[EE + e] + sp * w1[2 * EE + e] + b1[e];
    #pragma unroll
    for (int j = 0; j < EE; ++j) {
        float q = bq[j], k = bk[j], v = 0.f;
        #pragma unroll
        for (int c = 0; c < EE; ++c) {
            q += xr[c] * Wq[c * EE + j];
            k += xr[c] * Wk[c * EE + j];
            v += xr[c] * Wv[c * EE + j];
        }
        Qg[(size_t)i * EE + j] = (q >= 0.f) ? q : 0.2f * q;
        Kg[(size_t)i * EE + j] = (k >= 0.f) ? k : 0.2f * k;
        Vg[(size_t)i * EE + j] = v;
    }
    hist[i] = 0;
}

// ---- 3. edge histogram by destination row ----
__global__ void k_hist(const int* __restrict__ ei, int* __restrict__ hist) {
    int e = blockIdx.x * 256 + threadIdx.x;
    if (e >= NEDGE) return;
    atomicAdd(hist + ei[e], 1);
}

// ---- 4. exclusive prefix sum over 16384 counts (single block) ----
__global__ __launch_bounds__(256) void k_scan(const int* __restrict__ hist,
                                              int* __restrict__ offs,
                                              int* __restrict__ cnt) {
    __shared__ int part[256];
    int tid = threadIdx.x;
    int base = tid * 64;
    const int4* h4 = (const int4*)(hist + base);
    int sum = 0;
    #pragma unroll
    for (int i = 0; i < 16; ++i) { int4 v = h4[i]; sum += v.x + v.y + v.z + v.w; }
    part[tid] = sum;
    __syncthreads();
    for (int off = 1; off < 256; off <<= 1) {
        int v = (tid >= off) ? part[tid - off] : 0;
        __syncthreads();
        part[tid] += v;
        __syncthreads();
    }
    int run = (tid > 0) ? part[tid - 1] : 0;
    for (int i = 0; i < 64; ++i) {
        offs[base + i] = run;
        cnt[base + i] = run;
        run += hist[base + i];
    }
}

// ---- 5. scatter edge columns into destination buckets ----
__global__ void k_scatter(const int* __restrict__ ei, int* __restrict__ cnt,
                          int* __restrict__ ecol) {
    int e = blockIdx.x * 256 + threadIdx.x;
    if (e >= NEDGE) return;
    int r = ei[e], c = ei[NEDGE + e];
    int pos = atomicAdd(cnt + r, 1);
    ecol[pos] = c;
}

// ---- 6. per-row gather + online softmax + aggregate ----
__global__ __launch_bounds__(256) void k_gatagg(const int* __restrict__ ecol,
                                                const int* __restrict__ offs,
                                                const int* __restrict__ hist,
                                                const float* __restrict__ Qg,
                                                const float* __restrict__ Kg,
                                                const float* __restrict__ Vg,
                                                const float* __restrict__ gbias,
                                                float* __restrict__ hg) {
    int row = __builtin_amdgcn_readfirstlane(blockIdx.x * 4 + (threadIdx.x >> 6));
    int lane = threadIdx.x & 63;
    const float* Qr = Qg + (size_t)row * EE;     // wave-uniform -> scalar loads
    float q0 = Qr[0], q1 = Qr[1], q2 = Qr[2], q3 = Qr[3];
    float q4 = Qr[4], q5 = Qr[5], q6 = Qr[6], q7 = Qr[7];
    int beg = offs[row], deg = hist[row];
    int total = deg + 1;                         // + self-loop
    float m = -INFINITY, l = 0.f;
    float acc[EE];
    #pragma unroll
    for (int j = 0; j < EE; ++j) acc[j] = 0.f;
    for (int base = 0; base < total; base += 64) {
        int idx = base + lane;
        int c = row;                             // self-loop / inactive default
        if (idx < deg) c = ecol[beg + idx];
        const float4* K4 = (const float4*)(Kg + (size_t)c * EE);
        float4 ka = K4[0], kb = K4[1];
        float s = q0*ka.x + q1*ka.y + q2*ka.z + q3*ka.w
                + q4*kb.x + q5*kb.y + q6*kb.z + q7*kb.w;
        if (idx >= total) s = -INFINITY;
        float pm = s;
        #pragma unroll
        for (int off = 32; off > 0; off >>= 1) pm = fmaxf(pm, __shfl_xor(pm, off));
        float nm = fmaxf(m, pm);
        float scale = __expf(m - nm);
        float p = (idx < total) ? __expf(s - nm) : 0.f;
        float ps = p;
        #pragma unroll
        for (int off = 32; off > 0; off >>= 1) ps += __shfl_xor(ps, off);
        l = l * scale + ps;
        const float4* V4 = (const float4*)(Vg + (size_t)c * EE);
        float4 va = V4[0], vb = V4[1];
        float pv[EE] = {p*va.x, p*va.y, p*va.z, p*va.w, p*vb.x, p*vb.y, p*vb.z, p*vb.w};
        #pragma unroll
        for (int j = 0; j < EE; ++j) {
            float t = pv[j];
            #pragma unroll
            for (int off = 32; off > 0; off >>= 1) t += __shfl_xor(t, off);
            acc[j] = acc[j] * scale + t;
        }
        m = nm;
    }
    if (lane < EE)
        hg[(size_t)row * EE + lane] = acc[lane] / l + gbias[lane];
}

// ---- 7. qkv conv -> Fnat bf16 [b][n][o], o = l*24+c ----
__global__ __launch_bounds__(256) void k_qkvF(const float* __restrict__ hg,
                                              const float* __restrict__ qw,
                                              const float* __restrict__ qb,
                                              unsigned short* __restrict__ Fq) {
    int n0 = blockIdx.x * 32;
    int b = blockIdx.y;
    __shared__ float hs[34 * EE];        // rows n0-1 .. n0+32
    int tid = threadIdx.x;
    for (int i = tid; i < 34 * EE; i += 256) {
        int nn = n0 - 1 + (i >> 3);
        hs[i] = (nn >= 0 && nn < NND) ? hg[((size_t)b * NND + nn) * EE + (i & 7)] : 0.f;
    }
    __syncthreads();
    #pragma unroll
    for (int pass = 0; pass < 2; ++pass) {
        float w[3][24], bias[3];
        #pragma unroll
        for (int rr = 0; rr < 3; ++rr) {
            int o = tid + (pass * 3 + rr) * 256;
            bias[rr] = qb[o];
            #pragma unroll
            for (int kk = 0; kk < 24; ++kk) w[rr][kk] = qw[kk * OCC + o];
        }
        for (int nn = 0; nn < 32; ++nn) {
            const float* hv = &hs[nn * EE];
            float a0 = bias[0], a1 = bias[1], a2 = bias[2];
            #pragma unroll
            for (int kk = 0; kk < 24; ++kk) {
                float h = hv[kk];
                a0 += h * w[0][kk]; a1 += h * w[1][kk]; a2 += h * w[2][kk];
            }
            unsigned short* dst = Fq + ((size_t)b * NND + n0 + nn) * OCC + tid + pass * 768;
            dst[0]   = f2bf(a0);
            dst[256] = f2bf(a1);
            dst[512] = f2bf(a2);
        }
    }
}

// ---- 8. S partials via MFMA, 32-node chunks (4 sub-tiles of 8 nodes) ----
// q[t][f=n*24+c] = Fnat[n][t*24+c]; k[s][f] = Fnat[n+1365][s*24+c+8] (c<16)
//                                           / Fnat[n+1366][s*24+c-16] (c>=16)
__global__ __launch_bounds__(256) void k_attnS(const unsigned short* __restrict__ Fq,
                                               float* __restrict__ Spart) {
    int ch = blockIdx.x, b = blockIdx.y;
    __shared__ unsigned short qt[64 * 200];
    __shared__ unsigned short kt[64 * 200];
    int tid = threadIdx.x;
    int t = tid & 63, nl0 = tid >> 6;
    const unsigned short* Fb = Fq + (size_t)b * NND * OCC;
    short8 z = {0,0,0,0,0,0,0,0};
    int lane = tid & 63, wv = tid >> 6;
    int fr = lane & 15, fk = (lane >> 4) * 8;
    f32x4 accs[4] = {{0,0,0,0},{0,0,0,0},{0,0,0,0},{0,0,0,0}};
    for (int sub = 0; sub < 4; ++sub) {
        int n0 = ch * 32 + sub * 8;
        if (sub) __syncthreads();
        #pragma unroll
        for (int h = 0; h < 2; ++h) {
            int nl = nl0 + h * 4;
            int n = n0 + nl;
            short8 q0 = z, q1 = z, q2 = z;
            if (n <= 682) {
                const short8* p = (const short8*)(Fb + (size_t)n * OCC + t * 24);
                q0 = p[0]; q1 = p[1];
                if (n < 682) q2 = p[2];
            }
            *(short8*)(&qt[t * 200 + nl * 24 + 0])  = q0;
            *(short8*)(&qt[t * 200 + nl * 24 + 8])  = q1;
            *(short8*)(&qt[t * 200 + nl * 24 + 16]) = q2;
            short8 k0 = z, k1 = z, k2 = z;
            if (n <= 682) {
                const short8* p = (const short8*)(Fb + (size_t)(n + 1365) * OCC + t * 24 + 8);
                k0 = p[0]; k1 = p[1];
            }
            if (n <= 681) {
                const short8* p2 = (const short8*)(Fb + (size_t)(n + 1366) * OCC + t * 24);
                k2 = p2[0];
            }
            *(short8*)(&kt[t * 200 + nl * 24 + 0])  = k0;
            *(short8*)(&kt[t * 200 + nl * 24 + 8])  = k1;
            *(short8*)(&kt[t * 200 + nl * 24 + 16]) = k2;
        }
        __syncthreads();
        short8 afr[6];
        #pragma unroll
        for (int ks = 0; ks < 6; ++ks)
            afr[ks] = *(const short8*)(&qt[(wv * 16 + fr) * 200 + ks * 32 + fk]);
        #pragma unroll
        for (int srow = 0; srow < 4; ++srow) {
            #pragma unroll
            for (int ks = 0; ks < 6; ++ks) {
                short8 bfr = *(const short8*)(&kt[(srow * 16 + fr) * 200 + ks * 32 + fk]);
                accs[srow] = __builtin_amdgcn_mfma_f32_16x16x32_bf16(afr[ks], bfr, accs[srow], 0, 0, 0);
            }
        }
    }
    #pragma unroll
    for (int srow = 0; srow < 4; ++srow) {
        float* dst = Spart + (((size_t)ch * BSZ + b) * LLH + wv * 16 + (lane >> 4) * 4) * LLH
                   + srow * 16 + fr;
        #pragma unroll
        for (int r = 0; r < 4; ++r) dst[r * LLH] = accs[srow][r];
    }
}

// ---- 9. reduce partials + row softmax -> atT[b][s][t] ----
__global__ void k_softmax(const float* __restrict__ Spart, float* __restrict__ atT) {
    int b = blockIdx.x >> 6, t = blockIdx.x & 63;
    int s = threadIdx.x;
    float v = 0.f;
    for (int ch = 0; ch < NCHK; ++ch)
        v += Spart[(((size_t)ch * BSZ + b) * LLH + t) * LLH + s];
    float m = v;
    #pragma unroll
    for (int off = 32; off > 0; off >>= 1) m = fmaxf(m, __shfl_xor(m, off));
    float e = __expf(v - m);
    float sum = e;
    #pragma unroll
    for (int off = 32; off > 0; off >>= 1) sum += __shfl_xor(sum, off);
    atT[((size_t)b * LLH + s) * LLH + t] = e / sum;
}

// ---- 10. out[b][t][d] = sum_s atT[b][s][t] * v[s][d] ----
__global__ __launch_bounds__(256) void k_attnV(const unsigned short* __restrict__ Fq,
                                               const float* __restrict__ atT,
                                               float* __restrict__ out) {
    int b = blockIdx.y;
    int d = blockIdx.x * 64 + (threadIdx.x & 63);
    int t0 = __builtin_amdgcn_readfirstlane((threadIdx.x >> 6) * 16);
    int f = d + DQ;
    int n = f / 24, c = f - n * 24;
    const unsigned short* vcol = Fq + ((size_t)b * NND + n) * OCC + c;
    const float* arow = atT + (size_t)b * LLH * LLH + t0;
    float acc[16];
    #pragma unroll
    for (int tt = 0; tt < 16; ++tt) acc[tt] = 0.f;
    #pragma unroll 4
    for (int s = 0; s < LLH; ++s) {
        float vv = bf2f(vcol[s * 24]);
        #pragma unroll
        for (int tt = 0; tt < 16; ++tt)
            acc[tt] += arow[s * LLH + tt] * vv;
    }
    float* ob = out + ((size_t)b * LLH + t0) * DQ + d;
    #pragma unroll
    for (int tt = 0; tt < 16; ++tt) ob[(size_t)tt * DQ] = acc[tt];
}

extern "C" void kernel_launch(void* const* d_in, const int* in_sizes, int n_in,
                              void* d_out, int out_size, void* d_ws, size_t ws_size,
                              hipStream_t stream) {
    (void)in_sizes; (void)n_in; (void)out_size; (void)ws_size;
    const float* latent = (const float*)d_in[0];
    const int*   ei     = (const int*)d_in[1];
    const float* Wd     = (const float*)d_in[2];
    const float* bd     = (const float*)d_in[3];
    const float* w1     = (const float*)d_in[4];
    const float* b1     = (const float*)d_in[5];
    const float* Wq     = (const float*)d_in[6];
    const float* bq     = (const float*)d_in[7];
    const float* Wk     = (const float*)d_in[8];
    const float* bk     = (const float*)d_in[9];
    const float* Wv     = (const float*)d_in[10];
    const float* gbias  = (const float*)d_in[11];
    const float* qw     = (const float*)d_in[12];
    const float* qb     = (const float*)d_in[13];
    float* out = (float*)d_out;

    float* ws     = (float*)d_ws;
    float* pdense = ws;                          // 8*8*2048 = 131072
    float* Qg     = pdense + 64 * NND;           // 131072
    float* Kg     = Qg + BNN * EE;               // 131072
    float* Vg     = Kg + BNN * EE;               // 131072
    float* hg     = Vg + BNN * EE;               // 131072
    int*   hist   = (int*)(hg + BNN * EE);       // 16384
    int*   offs   = hist + BNN;                  // 16384
    int*   cnt    = offs + BNN;                  // 16384
    int*   ecol   = cnt + BNN;                   // 524288
    float* Spart  = (float*)(ecol + NEDGE);      // 22*8*64*64 = 720896
    float* atT    = Spart + (size_t)NCHK * BSZ * LLH * LLH;  // 32768
    unsigned short* Fq = (unsigned short*)(atT + BSZ * LLH * LLH);  // 25165824 bf16

    k_densep<<<dim3(64, 8), dim3(256), 0, stream>>>(latent, Wd, pdense);
    k_gat<<<dim3(256), dim3(64), 0, stream>>>(pdense, bd, w1, b1, Wq, bq, Wk, bk, Wv,
                                              Qg, Kg, Vg, hist);
    k_hist<<<dim3(NEDGE / 256), dim3(256), 0, stream>>>(ei, hist);
    k_scan<<<dim3(1), dim3(256), 0, stream>>>(hist, offs, cnt);
    k_scatter<<<dim3(NEDGE / 256), dim3(256), 0, stream>>>(ei, cnt, ecol);
    k_gatagg<<<dim3(BNN / 4), dim3(256), 0, stream>>>(ecol, offs, hist,
                                                      Qg, Kg, Vg, gbias, hg);
    k_qkvF<<<dim3(64, 8), dim3(256), 0, stream>>>(hg, qw, qb, Fq);
    k_attnS<<<dim3(NCHK, 8), dim3(256), 0, stream>>>(Fq, Spart);
    k_softmax<<<dim3(512), dim3(64), 0, stream>>>(Spart, atT);
    k_attnV<<<dim3(256, 8), dim3(256), 0, stream>>>(Fq, atT, out);
}

// Round 8
// 142.030 us; speedup vs baseline: 2.6762x; 1.0324x over previous
//
#include <hip/hip_runtime.h>
#include <hip/hip_bf16.h>
#include <math.h>

#define BSZ 8
#define DDIM 512
#define NND 2048
#define EE 8
#define LLH 64
#define NEDGE 524288
#define BNN 16384          // BSZ*NND
#define OCC 1536           // 3*EE*LLH
#define DQ 16384           // per-third flat d dimension
#define NCHK 22            // attnS node-chunks (32 nodes = 768 f each, covers n 0..703)

typedef __attribute__((ext_vector_type(8))) short short8;
typedef __attribute__((ext_vector_type(4))) float f32x4;

__device__ inline unsigned short f2bf(float x) {
    __hip_bfloat16 h = __float2bfloat16(x);
    return __builtin_bit_cast(unsigned short, h);
}
__device__ inline float bf2f(unsigned short u) {
    return __uint_as_float(((unsigned int)u) << 16);
}

// ---- 1. dense partials + zero hist ----
// grid (64 n-blocks, 8 d-splits), block 256 = 32 n x 8 b
__global__ __launch_bounds__(256) void k_densep(const float* __restrict__ latent,
                                                const float* __restrict__ Wd,
                                                float* __restrict__ pdense,
                                                int* __restrict__ hist) {
    int n0 = blockIdx.x * 32, d0 = blockIdx.y * 64;
    __shared__ float lat[8][64];
    int tid = threadIdx.x;
    if (blockIdx.y == 0) hist[blockIdx.x * 256 + tid] = 0;
    #pragma unroll
    for (int r = 0; r < 2; ++r) {
        int i = r * 256 + tid;
        lat[i >> 6][i & 63] = latent[(i >> 6) * DDIM + d0 + (i & 63)];
    }
    __syncthreads();
    int nl = tid & 31, b = tid >> 5;
    const float* wp = Wd + (size_t)d0 * NND + n0 + nl;
    float acc = 0.f;
    #pragma unroll 8
    for (int d = 0; d < 64; ++d) acc += lat[b][d] * wp[(size_t)d * NND];
    pdense[((size_t)blockIdx.y * BSZ + b) * NND + n0 + nl] = acc;
}

// ---- 2. fused: reduce partials -> conv1 -> GAT QKV projections + edge hist ----
__global__ __launch_bounds__(64) void k_gat(const float* __restrict__ pdense,
                                            const float* __restrict__ bd,
                                            const float* __restrict__ w1,
                                            const float* __restrict__ b1,
                                            const float* __restrict__ Wq, const float* __restrict__ bq,
                                            const float* __restrict__ Wk, const float* __restrict__ bk,
                                            const float* __restrict__ Wv,
                                            const int* __restrict__ ei,
                                            float* __restrict__ Qg, float* __restrict__ Kg,
                                            float* __restrict__ Vg, int* __restrict__ hist) {
    int i = blockIdx.x * 64 + threadIdx.x;
    int b = i >> 11, n = i & (NND - 1);
    float sm = 0.f, s0 = 0.f, sp = 0.f;
    #pragma unroll
    for (int ds = 0; ds < 8; ++ds) {
        const float* p = pdense + ((size_t)ds * BSZ + b) * NND + n;
        if (n > 0) sm += p[-1];
        s0 += p[0];
        if (n < NND - 1) sp += p[1];
    }
    if (n > 0) sm += bd[n - 1];
    s0 += bd[n];
    if (n < NND - 1) sp += bd[n + 1];
    float xr[EE];
    #pragma unroll
    for (int e = 0; e < EE; ++e)
        xr[e] = sm * w1[e] + s0 * w1[EE + e] + sp * w1[2 * EE + e] + b1[e];
    #pragma unroll
    for (int j = 0; j < EE; ++j) {
        float q = bq[j], k = bk[j], v = 0.f;
        #pragma unroll
        for (int c = 0; c < EE; ++c) {
            q += xr[c] * Wq[c * EE + j];
            k += xr[c] * Wk[c * EE + j];
            v += xr[c] * Wv[c * EE + j];
        }
        Qg[(size_t)i * EE + j] = (q >= 0.f) ? q : 0.2f * q;
        Kg[(size_t)i * EE + j] = (k >= 0.f) ? k : 0.2f * k;
        Vg[(size_t)i * EE + j] = v;
    }
    // edge histogram: coalesced grid-stride over rows
    #pragma unroll 4
    for (int j = 0; j < 32; ++j)
        atomicAdd(hist + ei[i + j * BNN], 1);
}

// ---- 3. exclusive prefix sum over 16384 counts (1024 threads, shuffle scan) ----
__global__ __launch_bounds__(1024) void k_scan(const int* __restrict__ hist,
                                               int* __restrict__ offs,
                                               int* __restrict__ cnt) {
    int tid = threadIdx.x;
    int lane = tid & 63, wv = tid >> 6;
    const int4* hp = (const int4*)(hist + tid * 16);
    int4 a = hp[0], b4 = hp[1], c4 = hp[2], d4 = hp[3];
    int h[16] = {a.x, a.y, a.z, a.w, b4.x, b4.y, b4.z, b4.w,
                 c4.x, c4.y, c4.z, c4.w, d4.x, d4.y, d4.z, d4.w};
    int mysum = 0;
    #pragma unroll
    for (int i = 0; i < 16; ++i) mysum += h[i];
    int inc = mysum;
    #pragma unroll
    for (int off = 1; off < 64; off <<= 1) {
        int u = __shfl_up(inc, off, 64);
        if (lane >= off) inc += u;
    }
    __shared__ int wtot[16];
    if (lane == 63) wtot[wv] = inc;
    __syncthreads();
    if (tid < 16) {
        int t = wtot[tid];
        #pragma unroll
        for (int off = 1; off < 16; off <<= 1) {
            int u = __shfl_up(t, off, 16);
            if (tid >= off) t += u;
        }
        wtot[tid] = t;
    }
    __syncthreads();
    int run = (wv ? wtot[wv - 1] : 0) + inc - mysum;
    #pragma unroll
    for (int i = 0; i < 16; ++i) {
        offs[tid * 16 + i] = run;
        cnt[tid * 16 + i] = run;
        run += h[i];
    }
}

// ---- 4. scatter edge columns into destination buckets ----
__global__ void k_scatter(const int* __restrict__ ei, int* __restrict__ cnt,
                          int* __restrict__ ecol) {
    int e = blockIdx.x * 256 + threadIdx.x;
    if (e >= NEDGE) return;
    int r = ei[e], c = ei[NEDGE + e];
    int pos = atomicAdd(cnt + r, 1);
    ecol[pos] = c;
}

// ---- 5. per-row gather + online softmax + aggregate ----
__global__ __launch_bounds__(256) void k_gatagg(const int* __restrict__ ecol,
                                                const int* __restrict__ offs,
                                                const int* __restrict__ hist,
                                                const float* __restrict__ Qg,
                                                const float* __restrict__ Kg,
                                                const float* __restrict__ Vg,
                                                const float* __restrict__ gbias,
                                                float* __restrict__ hg) {
    int row = __builtin_amdgcn_readfirstlane(blockIdx.x * 4 + (threadIdx.x >> 6));
    int lane = threadIdx.x & 63;
    const float* Qr = Qg + (size_t)row * EE;     // wave-uniform -> scalar loads
    float q0 = Qr[0], q1 = Qr[1], q2 = Qr[2], q3 = Qr[3];
    float q4 = Qr[4], q5 = Qr[5], q6 = Qr[6], q7 = Qr[7];
    int beg = offs[row], deg = hist[row];
    int total = deg + 1;                         // + self-loop
    float m = -INFINITY, l = 0.f;
    float acc[EE];
    #pragma unroll
    for (int j = 0; j < EE; ++j) acc[j] = 0.f;
    for (int base = 0; base < total; base += 64) {
        int idx = base + lane;
        int c = row;                             // self-loop / inactive default
        if (idx < deg) c = ecol[beg + idx];
        const float4* K4 = (const float4*)(Kg + (size_t)c * EE);
        float4 ka = K4[0], kb = K4[1];
        float s = q0*ka.x + q1*ka.y + q2*ka.z + q3*ka.w
                + q4*kb.x + q5*kb.y + q6*kb.z + q7*kb.w;
        if (idx >= total) s = -INFINITY;
        float pm = s;
        #pragma unroll
        for (int off = 32; off > 0; off >>= 1) pm = fmaxf(pm, __shfl_xor(pm, off));
        float nm = fmaxf(m, pm);
        float scale = __expf(m - nm);
        float p = (idx < total) ? __expf(s - nm) : 0.f;
        float ps = p;
        #pragma unroll
        for (int off = 32; off > 0; off >>= 1) ps += __shfl_xor(ps, off);
        l = l * scale + ps;
        const float4* V4 = (const float4*)(Vg + (size_t)c * EE);
        float4 va = V4[0], vb = V4[1];
        float pv[EE] = {p*va.x, p*va.y, p*va.z, p*va.w, p*vb.x, p*vb.y, p*vb.z, p*vb.w};
        #pragma unroll
        for (int j = 0; j < EE; ++j) {
            float t = pv[j];
            #pragma unroll
            for (int off = 32; off > 0; off >>= 1) t += __shfl_xor(t, off);
            acc[j] = acc[j] * scale + t;
        }
        m = nm;
    }
    if (lane < EE)
        hg[(size_t)row * EE + lane] = acc[lane] / l + gbias[lane];
}

// ---- 6. qkv conv -> Fnat bf16 [b][n][o]; LDS-staged coalesced short8 stores ----
__global__ __launch_bounds__(256) void k_qkvF(const float* __restrict__ hg,
                                              const float* __restrict__ qw,
                                              const float* __restrict__ qb,
                                              unsigned short* __restrict__ Fq) {
    int n0 = blockIdx.x * 32;
    int b = blockIdx.y;
    __shared__ float hs[34 * EE];        // rows n0-1 .. n0+32
    __shared__ unsigned short st[32 * 768];   // 48 KB staging
    int tid = threadIdx.x;
    for (int i = tid; i < 34 * EE; i += 256) {
        int nn = n0 - 1 + (i >> 3);
        hs[i] = (nn >= 0 && nn < NND) ? hg[((size_t)b * NND + nn) * EE + (i & 7)] : 0.f;
    }
    __syncthreads();
    #pragma unroll
    for (int pass = 0; pass < 2; ++pass) {
        if (pass) __syncthreads();
        float w[3][24], bias[3];
        #pragma unroll
        for (int rr = 0; rr < 3; ++rr) {
            int o = pass * 768 + rr * 256 + tid;
            bias[rr] = qb[o];
            #pragma unroll
            for (int kk = 0; kk < 24; ++kk) w[rr][kk] = qw[kk * OCC + o];
        }
        for (int nn = 0; nn < 32; ++nn) {
            const float* hv = &hs[nn * EE];
            float a0 = bias[0], a1 = bias[1], a2 = bias[2];
            #pragma unroll
            for (int kk = 0; kk < 24; ++kk) {
                float h = hv[kk];
                a0 += h * w[0][kk]; a1 += h * w[1][kk]; a2 += h * w[2][kk];
            }
            st[nn * 768 + tid]       = f2bf(a0);
            st[nn * 768 + tid + 256] = f2bf(a1);
            st[nn * 768 + tid + 512] = f2bf(a2);
        }
        __syncthreads();
        unsigned short* dstbase = Fq + ((size_t)b * NND + n0) * OCC + pass * 768;
        #pragma unroll
        for (int it = 0; it < 12; ++it) {
            int idx8 = it * 256 + tid;           // 0..3071
            int row = idx8 / 96, col8 = idx8 - row * 96;
            *(short8*)(dstbase + (size_t)row * OCC + col8 * 8) =
                *(const short8*)(&st[row * 768 + col8 * 8]);
        }
    }
}

// ---- 7. S partials via MFMA, 32-node chunks (4 sub-tiles of 8 nodes) ----
__global__ __launch_bounds__(256) void k_attnS(const unsigned short* __restrict__ Fq,
                                               float* __restrict__ Spart) {
    int ch = blockIdx.x, b = blockIdx.y;
    __shared__ unsigned short qt[64 * 200];
    __shared__ unsigned short kt[64 * 200];
    int tid = threadIdx.x;
    int t = tid & 63, nl0 = tid >> 6;
    const unsigned short* Fb = Fq + (size_t)b * NND * OCC;
    short8 z = {0,0,0,0,0,0,0,0};
    int lane = tid & 63, wv = tid >> 6;
    int fr = lane & 15, fk = (lane >> 4) * 8;
    f32x4 accs[4] = {{0,0,0,0},{0,0,0,0},{0,0,0,0},{0,0,0,0}};
    for (int sub = 0; sub < 4; ++sub) {
        int n0 = ch * 32 + sub * 8;
        if (sub) __syncthreads();
        #pragma unroll
        for (int h = 0; h < 2; ++h) {
            int nl = nl0 + h * 4;
            int n = n0 + nl;
            short8 q0 = z, q1 = z, q2 = z;
            if (n <= 682) {
                const short8* p = (const short8*)(Fb + (size_t)n * OCC + t * 24);
                q0 = p[0]; q1 = p[1];
                if (n < 682) q2 = p[2];
            }
            *(short8*)(&qt[t * 200 + nl * 24 + 0])  = q0;
            *(short8*)(&qt[t * 200 + nl * 24 + 8])  = q1;
            *(short8*)(&qt[t * 200 + nl * 24 + 16]) = q2;
            short8 k0 = z, k1 = z, k2 = z;
            if (n <= 682) {
                const short8* p = (const short8*)(Fb + (size_t)(n + 1365) * OCC + t * 24 + 8);
                k0 = p[0]; k1 = p[1];
            }
            if (n <= 681) {
                const short8* p2 = (const short8*)(Fb + (size_t)(n + 1366) * OCC + t * 24);
                k2 = p2[0];
            }
            *(short8*)(&kt[t * 200 + nl * 24 + 0])  = k0;
            *(short8*)(&kt[t * 200 + nl * 24 + 8])  = k1;
            *(short8*)(&kt[t * 200 + nl * 24 + 16]) = k2;
        }
        __syncthreads();
        short8 afr[6];
        #pragma unroll
        for (int ks = 0; ks < 6; ++ks)
            afr[ks] = *(const short8*)(&qt[(wv * 16 + fr) * 200 + ks * 32 + fk]);
        #pragma unroll
        for (int srow = 0; srow < 4; ++srow) {
            #pragma unroll
            for (int ks = 0; ks < 6; ++ks) {
                short8 bfr = *(const short8*)(&kt[(srow * 16 + fr) * 200 + ks * 32 + fk]);
                accs[srow] = __builtin_amdgcn_mfma_f32_16x16x32_bf16(afr[ks], bfr, accs[srow], 0, 0, 0);
            }
        }
    }
    #pragma unroll
    for (int srow = 0; srow < 4; ++srow) {
        float* dst = Spart + (((size_t)ch * BSZ + b) * LLH + wv * 16 + (lane >> 4) * 4) * LLH
                   + srow * 16 + fr;
        #pragma unroll
        for (int r = 0; r < 4; ++r) dst[r * LLH] = accs[srow][r];
    }
}

// ---- 8. reduce partials + row softmax -> atT[b][s][t] ----
__global__ void k_softmax(const float* __restrict__ Spart, float* __restrict__ atT) {
    int b = blockIdx.x >> 6, t = blockIdx.x & 63;
    int s = threadIdx.x;
    float v = 0.f;
    for (int ch = 0; ch < NCHK; ++ch)
        v += Spart[(((size_t)ch * BSZ + b) * LLH + t) * LLH + s];
    float m = v;
    #pragma unroll
    for (int off = 32; off > 0; off >>= 1) m = fmaxf(m, __shfl_xor(m, off));
    float e = __expf(v - m);
    float sum = e;
    #pragma unroll
    for (int off = 32; off > 0; off >>= 1) sum += __shfl_xor(sum, off);
    atT[((size_t)b * LLH + s) * LLH + t] = e / sum;
}

// ---- 9. out[b][t][d] = sum_s atT[b][s][t] * v[s][d]; v staged in LDS ----
__global__ __launch_bounds__(256) void k_attnV(const unsigned short* __restrict__ Fq,
                                               const float* __restrict__ atT,
                                               float* __restrict__ out) {
    int b = blockIdx.y;
    int d0 = blockIdx.x * 64;
    int tid = threadIdx.x;
    __shared__ unsigned short vt[64 * 64];
    const unsigned short* Fb = Fq + (size_t)b * NND * OCC;
    #pragma unroll
    for (int r = 0; r < 16; ++r) {
        int idx = r * 256 + tid;
        int s = idx >> 6, d = idx & 63;
        int f = DQ + d0 + d;
        int n = f / 24, c = f - n * 24;
        vt[s * 64 + d] = Fb[(size_t)n * OCC + s * 24 + c];
    }
    __syncthreads();
    int lane = tid & 63;
    int t0 = __builtin_amdgcn_readfirstlane((tid >> 6) * 16);
    const float* arow = atT + (size_t)b * LLH * LLH + t0;
    float acc[16];
    #pragma unroll
    for (int tt = 0; tt < 16; ++tt) acc[tt] = 0.f;
    #pragma unroll 4
    for (int s = 0; s < LLH; ++s) {
        float vv = bf2f(vt[s * 64 + lane]);
        #pragma unroll
        for (int tt = 0; tt < 16; ++tt)
            acc[tt] += arow[s * LLH + tt] * vv;
    }
    float* ob = out + ((size_t)b * LLH + t0) * DQ + d0 + lane;
    #pragma unroll
    for (int tt = 0; tt < 16; ++tt) ob[(size_t)tt * DQ] = acc[tt];
}

extern "C" void kernel_launch(void* const* d_in, const int* in_sizes, int n_in,
                              void* d_out, int out_size, void* d_ws, size_t ws_size,
                              hipStream_t stream) {
    (void)in_sizes; (void)n_in; (void)out_size; (void)ws_size;
    const float* latent = (const float*)d_in[0];
    const int*   ei     = (const int*)d_in[1];
    const float* Wd     = (const float*)d_in[2];
    const float* bd     = (const float*)d_in[3];
    const float* w1     = (const float*)d_in[4];
    const float* b1     = (const float*)d_in[5];
    const float* Wq     = (const float*)d_in[6];
    const float* bq     = (const float*)d_in[7];
    const float* Wk     = (const float*)d_in[8];
    const float* bk     = (const float*)d_in[9];
    const float* Wv     = (const float*)d_in[10];
    const float* gbias  = (const float*)d_in[11];
    const float* qw     = (const float*)d_in[12];
    const float* qb     = (const float*)d_in[13];
    float* out = (float*)d_out;

    float* ws     = (float*)d_ws;
    float* pdense = ws;                          // 131072
    float* Qg     = pdense + 64 * NND;           // 131072
    float* Kg     = Qg + BNN * EE;               // 131072
    float* Vg     = Kg + BNN * EE;               // 131072
    float* hg     = Vg + BNN * EE;               // 131072
    int*   hist   = (int*)(hg + BNN * EE);       // 16384
    int*   offs   = hist + BNN;                  // 16384
    int*   cnt    = offs + BNN;                  // 16384
    int*   ecol   = cnt + BNN;                   // 524288
    float* Spart  = (float*)(ecol + NEDGE);      // 22*8*64*64 = 720896
    float* atT    = Spart + (size_t)NCHK * BSZ * LLH * LLH;  // 32768
    unsigned short* Fq = (unsigned short*)(atT + BSZ * LLH * LLH);  // 25165824 bf16

    k_densep<<<dim3(64, 8), dim3(256), 0, stream>>>(latent, Wd, pdense, hist);
    k_gat<<<dim3(256), dim3(64), 0, stream>>>(pdense, bd, w1, b1, Wq, bq, Wk, bk, Wv,
                                              ei, Qg, Kg, Vg, hist);
    k_scan<<<dim3(1), dim3(1024), 0, stream>>>(hist, offs, cnt);
    k_scatter<<<dim3(NEDGE / 256), dim3(256), 0, stream>>>(ei, cnt, ecol);
    k_gatagg<<<dim3(BNN / 4), dim3(256), 0, stream>>>(ecol, offs, hist,
                                                      Qg, Kg, Vg, gbias, hg);
    k_qkvF<<<dim3(64, 8), dim3(256), 0, stream>>>(hg, qw, qb, Fq);
    k_attnS<<<dim3(NCHK, 8), dim3(256), 0, stream>>>(Fq, Spart);
    k_softmax<<<dim3(512), dim3(64), 0, stream>>>(Spart, atT);
    k_attnV<<<dim3(256, 8), dim3(256), 0, stream>>>(Fq, atT, out);
}